// Round 13
// baseline (152.778 us; speedup 1.0000x reference)
//
#include <hip/hip_runtime.h>
#include <math.h>

#define NM    6400
#define DTL   64               // lanes; lane l covers dt = l and l+64
#define CHW   128              // samples per chunk
#define NCH   176              // chunks: 176*128 = 22528 >= 22050
#define NCP   (NCH / 2)        // chunk pairs: 88
#define NCHT  (NCH * CHW)
#define NCHP  (NCHT + 64)      // padded partial plane stride
#define MBT   32               // modes per LDS tile (32KB)
#define KT    4                // tiles per block -> 128 modes
#define MPB   (MBT * KT)
#define MGY   (NM / MPB)       // 50 partial planes
#define GX    (NCP / 4)        // 22 (4 waves x 1 chunk-pair each)

#define GEN_A ((NCP / 8) * NM) // 11*6400 state4 gen threads
#define GEN_B (NM * 8)         // cdP gen threads

typedef float v2f __attribute__((ext_vector_type(2)));

static __device__ __forceinline__ float softplusf(float x) {
    return log1pf(expf(-fabsf(x))) + fmaxf(x, 0.0f);
}
static __device__ __forceinline__ float sigmoidf(float x) {
    return 1.0f / (1.0f + expf(-x));
}

// EXACT fp32 sequence used by all passing rounds: mode id -> (A, omega, sigma)
static __device__ __forceinline__ void mode_const(
    int id, float mu_raw, float Dmu_raw, float T0mu_raw,
    float Ly_raw, float xo_raw, float yo_raw,
    float& A, float& omega, float& sigma)
{
    const float KF   = 1.0f / 44100.0f;
    const float PI_F = (float)M_PI;
    const double om2sq = (2.0 * M_PI * 500.0) * (2.0 * M_PI * 500.0);
    const float ALPHA_F  = (float)(3.0 * M_LN10 / om2sq * (om2sq / 6.0));
    const float BETA_F   = (float)(3.0 * M_LN10 / om2sq * (1.0 - 1.0 / 6.0));
    const float MAX_OM_F = (float)(10000.0 * 2.0 * M_PI);
    const float MIN_OM_F = (float)(20.0 * 2.0 * M_PI);
    const float KK_F     = (float)((1.0 / 44100.0) * (1.0 / 44100.0));

    float mu   = (softplusf(mu_raw)   + 1e-4f) * 2.43f;
    float Dmu  = (softplusf(Dmu_raw)  + 1e-4f) * 0.002452f;
    float T0mu = (softplusf(T0mu_raw) + 1e-4f) * 0.004115f;
    float Ly   = 1.1f + 2.9f * sigmoidf(Ly_raw);
    float xo   = 0.245f + 0.255f * sigmoidf(xo_raw);
    float yo   = __fadd_rn(__fmul_rn(0.51f, Ly),
                           __fmul_rn(__fmul_rn(0.49f, Ly), sigmoidf(yo_raw)));

    float mf = (float)(id / 80 + 1);
    float nf = (float)(id % 80 + 1);

    float am = __fmul_rn(__fmul_rn(mf, PI_F), 2.0f);
    float bn = __fdiv_rn(__fmul_rn(nf, PI_F), Ly);
    float g1 = __fadd_rn(__fmul_rn(am, am), __fmul_rn(bn, bn));
    float omega_sq = __fadd_rn(__fmul_rn(T0mu, g1),
                               __fmul_rn(__fmul_rn(Dmu, g1), g1));
    omega = sqrtf(fmaxf(omega_sq, 0.0f));
    float valid = (omega <= MAX_OM_F && omega >= MIN_OM_F) ? 1.0f : 0.0f;

    float xi_pi = (float)(0.05 * M_PI);
    float yi = __fmul_rn(0.1f, Ly);
    float InW = __fmul_rn(
        cosf(__fmul_rn(__fmul_rn(xi_pi, mf), 2.0f)),
        cosf(__fdiv_rn(__fmul_rn(__fmul_rn(yi, PI_F), nf), Ly)));
    float OutW = __fmul_rn(
        cosf(__fmul_rn(__fmul_rn(__fmul_rn(xo, PI_F), mf), 2.0f)),
        cosf(__fdiv_rn(__fmul_rn(__fmul_rn(yo, PI_F), nf), Ly)));

    sigma = __fadd_rn(ALPHA_F, __fmul_rn(BETA_F, __fmul_rn(omega, omega)));
    float ms = __fmul_rn(__fmul_rn(__fmul_rn(0.25f, mu), 0.5f), Ly);
    float P = __fmul_rn(
        __fdiv_rn(__fmul_rn(__fmul_rn(__fmul_rn(OutW, InW), KK_F),
                            expf(__fmul_rn(-sigma, KF))),
                  ms),
        valid);
    float den = __fadd_rn(sinf(__fmul_rn(omega, KF)), 1e-8f);
    A = __fdiv_rn(P, den);
}

// Fully parallel generation (~122K threads):
//  A: state4[cp][m] = {S(2cp),C(2cp),S(2cp+1),C(2cp+1)} closed-form
//  B: cdP[m*64+l]   = {R(l),R(l+64),I(l),I(l+64)}  (R=dec*cos, I=dec*sin)
//  C: zero cnt + peakBits
__global__ __launch_bounds__(256) void gen_kernel(
    const float* __restrict__ mu_raw, const float* __restrict__ Dmu_raw,
    const float* __restrict__ T0mu_raw, const float* __restrict__ Ly_raw,
    const float* __restrict__ xo_raw, const float* __restrict__ yo_raw,
    float4* __restrict__ state4, float4* __restrict__ cdP,
    unsigned int* __restrict__ cnt, unsigned int* __restrict__ peakBits)
{
    const float  KF     = 1.0f / 44100.0f;
    const double Kd     = 1.0 / 44100.0;
    const double TWO_PI = 6.283185307179586476925286766559;
    const double I2PI   = 0.15915494309189533576888376337251;

    int idx = blockIdx.x * blockDim.x + threadIdx.x;
    float mur = mu_raw[0], dmur = Dmu_raw[0], t0mur = T0mu_raw[0];
    float lyr = Ly_raw[0], xorw = xo_raw[0], yorw = yo_raw[0];

    if (idx < GEN_A) {
        int cpg = idx / NM, m = idx - cpg * NM;    // consecutive idx -> consecutive m
        float A, w, sg;
        mode_const(m, mur, dmur, t0mur, lyr, xorw, yorw, A, w, sg);
        #pragma unroll
        for (int i = 0; i < 8; ++i) {
            int cp = cpg * 8 + i;
            float S[2], C[2];
            #pragma unroll
            for (int h = 0; h < 2; ++h) {
                int t0 = (2 * cp + h) * CHW;
                double ph = (double)t0 * (double)w * Kd;
                double q  = rint(ph * I2PI);
                float  r  = (float)fma(-q, TWO_PI, ph);
                float s0, c0;
                __sincosf(r, &s0, &c0);
                float env = A * __expf(-sg * (float)(t0 - 1) * KF);
                S[h] = env * s0; C[h] = env * c0;
            }
            state4[(size_t)cp * NM + m] = make_float4(S[0], C[0], S[1], C[1]);
        }
    } else if (idx < GEN_A + GEN_B) {
        int j = idx - GEN_A;
        int m = j >> 3, lg = j & 7;
        float A, w, sg;
        mode_const(m, mur, dmur, t0mur, lyr, xorw, yorw, A, w, sg);
        (void)A;
        #pragma unroll
        for (int i = 0; i < 8; ++i) {
            int l = lg * 8 + i;
            float R[2], I[2];
            #pragma unroll
            for (int h = 0; h < 2; ++h) {
                int dt = l + h * 64;
                double ph = (double)dt * (double)w * Kd;
                double q  = rint(ph * I2PI);
                float  r  = (float)fma(-q, TWO_PI, ph);
                float sr, cr;
                __sincosf(r, &sr, &cr);
                float dec = __expf(-sg * (float)dt * KF);
                R[h] = dec * cr; I[h] = dec * sr;
            }
            cdP[(size_t)m * DTL + l] = make_float4(R[0], R[1], I[0], I[1]);
        }
    } else if (idx == GEN_A + GEN_B) {
        cnt[0] = 0u;
        peakBits[0] = 0u;
    }
}

// partial[y][t] over 128 modes/block, k-loop of 4 LDS-staged 32-mode tiles.
// Wave = one chunk pair (256 samples via v2f dt-halves). Inner loop touches
// ONLY LDS (cd tile, b128) + wave-uniform state (scalar loads) + v_pk_fma.
// Staging is register-prefetched one tile ahead. No atomics, no fences.
__global__ __launch_bounds__(256) void gemm_kernel(
    const float4* __restrict__ state4, const float4* __restrict__ cdP,
    float* __restrict__ partial)
{
    __shared__ float4 tile[MBT * DTL];             // 32 KB
    const int tid  = threadIdx.x;
    const int wv   = __builtin_amdgcn_readfirstlane(tid >> 6);  // provably uniform
    const int lane = tid & 63;
    const int mB0  = blockIdx.y * MPB;
    const int cp   = blockIdx.x * 4 + wv;          // wave's chunk pair

    float4 pre[8];
    {
        const float4* s0 = cdP + (size_t)mB0 * DTL;
        #pragma unroll
        for (int i = 0; i < 8; ++i) pre[i] = s0[i * 256 + tid];
    }

    v2f a0 = {0.0f, 0.0f}, a1 = {0.0f, 0.0f};
    for (int k = 0; k < KT; ++k) {
        #pragma unroll
        for (int i = 0; i < 8; ++i) tile[i * 256 + tid] = pre[i];
        __syncthreads();
        if (k + 1 < KT) {
            const float4* sn = cdP + (size_t)(mB0 + (k + 1) * MBT) * DTL;
            #pragma unroll
            for (int i = 0; i < 8; ++i) pre[i] = sn[i * 256 + tid];
        }
        const float4* st = state4 + (size_t)cp * NM + mB0 + k * MBT;
        #pragma unroll 8
        for (int m = 0; m < MBT; ++m) {
            float4 t = tile[m * DTL + lane];       // {R_l, R_l64, I_l, I_l64}
            float4 s = st[m];                      // uniform -> s_load
            v2f vR = {t.x, t.y};
            v2f vI = {t.z, t.w};
            a0 += vR * s.x;  a0 += vI * s.y;       // chunk 2cp:   S*R + C*I
            a1 += vR * s.z;  a1 += vI * s.w;       // chunk 2cp+1
        }
        __syncthreads();
    }

    float* p = partial + (size_t)blockIdx.y * NCHP + (size_t)(2 * cp) * CHW;
    p[lane]       = a0.x;                          // dt = l
    p[lane + 64]  = a0.y;                          // dt = l+64
    p[lane + 128] = a1.x;
    p[lane + 192] = a1.y;
}

// out[t] = sum_y partial[y][t]; per-block peak -> atomicMax bits; last of
// 87 blocks (counter + fence — cheap at this count, proven in R12) divides.
__global__ __launch_bounds__(256) void reduce_norm_kernel(
    const float* __restrict__ partial, float* __restrict__ out,
    unsigned int* __restrict__ cnt, unsigned int* __restrict__ peakBits, int T)
{
    const int tid = threadIdx.x;
    int t = blockIdx.x * 256 + tid;

    float v = 0.0f;
    if (t < T) {
        float b0 = 0.0f, b1 = 0.0f;
        const float* p = partial + t;
        #pragma unroll 5
        for (int y = 0; y < MGY; y += 2) {
            b0 += p[(size_t)(y    ) * NCHP];
            b1 += p[(size_t)(y + 1) * NCHP];
        }
        v = b0 + b1;
        out[t] = v;
    }

    float mx = fabsf(v);
    #pragma unroll
    for (int off = 32; off > 0; off >>= 1)
        mx = fmaxf(mx, __shfl_xor(mx, off, 64));
    __shared__ float red[4];
    __shared__ int sLast;
    const int wave = tid >> 6, lane = tid & 63;
    if (lane == 0) red[wave] = mx;
    __syncthreads();
    if (tid == 0) {
        float m = fmaxf(fmaxf(red[0], red[1]), fmaxf(red[2], red[3]));
        atomicMax(peakBits, __float_as_uint(m));   // all values >= 0
    }
    __threadfence();
    __syncthreads();
    if (tid == 0) {
        unsigned int old = atomicAdd(cnt, 1u);
        sLast = (old == gridDim.x - 1) ? 1 : 0;
    }
    __syncthreads();
    if (sLast) {
        __threadfence();
        float pk = __uint_as_float(atomicMax(peakBits, 0u)) + 1e-8f;
        for (int i = tid; i < T; i += 256)
            out[i] = __fdiv_rn(out[i], pk);
    }
}

extern "C" void kernel_launch(void* const* d_in, const int* in_sizes, int n_in,
                              void* d_out, int out_size, void* d_ws, size_t ws_size,
                              hipStream_t stream)
{
    const float* mu   = (const float*)d_in[0];
    const float* Dmu  = (const float*)d_in[1];
    const float* T0mu = (const float*)d_in[2];
    const float* Lyr  = (const float*)d_in[3];
    const float* xor_ = (const float*)d_in[4];
    const float* yor_ = (const float*)d_in[5];
    float* out = (float*)d_out;

    float4* state4 = (float4*)d_ws;                          // 88*6400*16 = 9.0 MB
    float4* cdP    = state4 + (size_t)NCP * NM;              // 6400*64*16 = 6.55 MB
    float*  partial = (float*)(cdP + (size_t)NM * DTL);      // 50*NCHP*4 = 4.5 MB
    unsigned int* cnt      = (unsigned int*)(partial + (size_t)MGY * NCHP);
    unsigned int* peakBits = cnt + 1;

    int T = out_size;
    int genItems = GEN_A + GEN_B + 1;

    gen_kernel<<<(genItems + 255) / 256, 256, 0, stream>>>(
        mu, Dmu, T0mu, Lyr, xor_, yor_, state4, cdP, cnt, peakBits);
    gemm_kernel<<<dim3(GX, MGY), 256, 0, stream>>>(state4, cdP, partial);
    reduce_norm_kernel<<<(T + 255) / 256, 256, 0, stream>>>(
        partial, out, cnt, peakBits, T);
}